// Round 4
// baseline (929.011 us; speedup 1.0000x reference)
//
#include <hip/hip_runtime.h>
#include <hip/hip_bf16.h>
#include <cstdint>
#include <math.h>

// Problem constants (from reference)
#define T_TOK 4096
#define E_EXP 64
#define KSEL  8
#define H_DIM 1024
#define F_DIM 512
#define C_CAP 1024

typedef __bf16 bf16x8 __attribute__((ext_vector_type(8)));
typedef __bf16 bf16x4 __attribute__((ext_vector_type(4)));
typedef float  f32x4  __attribute__((ext_vector_type(4)));

// async global->LDS 16B per lane: LDS dest is wave-uniform base + lane*16
__device__ __forceinline__ void async_cp16(const void* g, void* l) {
    __builtin_amdgcn_global_load_lds(
        (const __attribute__((address_space(1))) void*)g,
        (__attribute__((address_space(3))) void*)l, 16, 0, 0);
}

// ---------------- ws layout (bytes) ----------------
#define OFF_WT     ((size_t)0)
#define OFF_GWT    ((size_t)131072)
#define OFF_GTOK   ((size_t)393216)
#define OFF_MASKS  ((size_t)655360)
#define OFF_COUNTS ((size_t)688128)
#define OFF_XB     ((size_t)1 << 20)
#define OFF_WGT    ((size_t)9 << 20)
#define OFF_WUT    ((size_t)73 << 20)
#define OFF_HBUF   ((size_t)137 << 20)

// ---------------- router: fp64 scores (near-tie index exactness), top-8 ----------------
// NOTE: harness reads the whole d_out buffer as float32, so expert_index is stored
// as FLOAT VALUES (0.0..63.0).
__global__ __launch_bounds__(64) void router_kernel(
    const float* __restrict__ x, const float* __restrict__ wr,
    const float* __restrict__ bias,
    float* __restrict__ logits_out, float* __restrict__ idx_out,
    float* __restrict__ wt_buf, unsigned long long* __restrict__ masks,
    __bf16* __restrict__ xb)
{
    const int t = blockIdx.x;
    const int e = threadIdx.x;              // lane == expert
    const float4* x4 = (const float4*)(x + (size_t)t * H_DIM);
    const float4* w4 = (const float4*)(wr + (size_t)e * H_DIM);

    double acc = 0.0;
    #pragma unroll 4
    for (int i = 0; i < H_DIM / 4; i++) {
        float4 a = x4[i], b = w4[i];
        acc += (double)a.x * (double)b.x + (double)a.y * (double)b.y
             + (double)a.z * (double)b.z + (double)a.w * (double)b.w;
    }
    logits_out[(size_t)t * E_EXP + e] = (float)acc;

    #pragma unroll
    for (int i2 = 0; i2 < 4; i2++) {
        float4 a = x4[e * 4 + i2];
        bf16x4 v;
        v[0] = (__bf16)a.x; v[1] = (__bf16)a.y; v[2] = (__bf16)a.z; v[3] = (__bf16)a.w;
        *(bf16x4*)(xb + (size_t)t * H_DIM + (size_t)(e * 4 + i2) * 4) = v;
    }

    const double aff = 1.0 / (1.0 + exp(-acc));
    double cur = aff + (double)bias[e];
    double myw = 0.0; int myi = 0;
    double wsum = 0.0;
    unsigned long long msk = 0ull;

    #pragma unroll
    for (int k = 0; k < KSEL; k++) {
        double rv = cur; int ri = e;
        #pragma unroll
        for (int off = 32; off > 0; off >>= 1) {
            double ov = __shfl_xor(rv, off);
            int    oi = __shfl_xor(ri, off);
            if (ov > rv || (ov == rv && oi < ri)) { rv = ov; ri = oi; }
        }
        double wa = __shfl(aff, ri);
        wsum += wa;
        if (e == k)  { myi = ri; myw = wa; }
        if (e == ri) cur = -1e300;
        msk |= 1ull << ri;
    }
    if (e < KSEL) {
        idx_out[t * KSEL + e] = (float)myi;
        wt_buf[t * KSEL + e] = (float)(myw / wsum);
    }
    if (e == 0) masks[t] = msk;
}

// ---------------- scan: per-expert token-ordered gather lists ----------------
__global__ __launch_bounds__(64) void scan_kernel(
    const unsigned long long* __restrict__ masks,
    const float* __restrict__ idx_out, const float* __restrict__ wt_buf,
    int* __restrict__ gtok, float* __restrict__ gwt, int* __restrict__ counts)
{
    const int e = blockIdx.x;
    const int lane = threadIdx.x;
    int running = 0;
    for (int base = 0; base < T_TOK; base += 64) {
        const int t = base + lane;
        const int bit = (int)((masks[t] >> e) & 1ull);
        unsigned long long bal = __ballot(bit);
        int pre = __popcll(bal & ((1ull << lane) - 1ull));
        if (bit) {
            int pos = running + pre;
            if (pos < C_CAP) {
                float w = 0.f;
                #pragma unroll
                for (int j = 0; j < KSEL; j++)
                    if ((int)idx_out[t * KSEL + j] == e) w = wt_buf[t * KSEL + j];
                gtok[e * C_CAP + pos] = t;
                gwt[e * C_CAP + pos] = w;
            }
        }
        running += __popcll(bal);
    }
    if (lane == 0) counts[e] = running < C_CAP ? running : C_CAP;
}

// ---------------- transpose + fp32->bf16 cast, two sources fused ----------------
// in[e][R][Cc] -> out[e][Cc][R]; blockIdx.z selects (src0,dst0) for z<E, else (src1,dst1)
__global__ __launch_bounds__(256) void transpose_cast2(
    const float* __restrict__ in0, __bf16* __restrict__ out0,
    const float* __restrict__ in1, __bf16* __restrict__ out1, int R, int Cc)
{
    const int z = blockIdx.z;
    const int e = z & (E_EXP - 1);
    const float* in  = (z < E_EXP) ? in0  : in1;
    __bf16*      out = (z < E_EXP) ? out0 : out1;
    const int r0 = blockIdx.y * 32;
    const int c0 = blockIdx.x * 32;
    __shared__ float tile[32][33];
    const int tid = threadIdx.x;
    const int tc = tid & 31, tr = tid >> 5;
    const float* src = in + ((size_t)e * R + r0) * Cc + c0;
    #pragma unroll
    for (int p = 0; p < 4; p++)
        tile[tr + p * 8][tc] = src[(size_t)(tr + p * 8) * Cc + tc];
    __syncthreads();
    __bf16* dst = out + ((size_t)e * Cc + c0) * R + r0;
    #pragma unroll
    for (int p = 0; p < 4; p++)
        dst[(size_t)(tr + p * 8) * R + tc] = (__bf16)tile[tc][tr + p * 8];
}

// ---------------- GEMM tile config (m97 structure: BK=64, unpadded LDS, async staging) ----------------
#define BM  128
#define BK  64      // 128 B per LDS row, unpadded (global_load_lds requires lane-contiguous LDS)
#define BN1 64      // N tile for gate and for up
#define BN2 128     // N tile for down

// gate+up fused: h[e][c][f] = silu(g)*u, A rows gathered from xb by token id
__global__ __launch_bounds__(256) void gemm_gateup(
    const __bf16* __restrict__ xb, const __bf16* __restrict__ wgT,
    const __bf16* __restrict__ wuT, const int* __restrict__ gtok,
    const int* __restrict__ counts, __bf16* __restrict__ hbuf)
{
    const int e = blockIdx.z;
    const int count = counts[e];
    const int m0 = blockIdx.y * BM;
    if (m0 >= count) return;
    const int n0 = blockIdx.x * BN1;

    __shared__ __bf16 As [BM  * BK];   // 16 KB
    __shared__ __bf16 Bgs[BN1 * BK];   //  8 KB
    __shared__ __bf16 Bus[BN1 * BK];   //  8 KB

    const int tid  = threadIdx.x;
    const int lane = tid & 63;
    const int wave = tid >> 6;
    const int wm0 = (wave & 1) * 64;
    const int wn0 = (wave >> 1) * 32;
    const int q  = lane >> 4;
    const int ln = lane & 15;

    // staging geometry: one async_cp16 = 64 lanes * 16B = 1 KB = 8 rows of 128 B
    const int srow = lane >> 3;            // row within 8-row group
    const int selem = (lane & 7) * 8;      // bf16 elem offset within row

    // A: 16 groups of 8 rows; wave w stages groups s=0..3 -> rows w*32+s*8
    const __bf16* gA[4];
    __bf16* lA[4];
    #pragma unroll
    for (int s = 0; s < 4; s++) {
        const int r = wave * 32 + s * 8 + srow;
        int rr = m0 + r; if (rr > count - 1) rr = count - 1;   // clamp: results discarded later
        const int tok = gtok[e * C_CAP + rr];
        gA[s] = xb + (size_t)tok * H_DIM + selem;
        lA[s] = &As[(wave * 32 + s * 8) * BK];                 // wave-uniform base
    }
    // Bg/Bu: 8 groups each; wave w stages s=0..1 -> rows w*16+s*8
    const __bf16* gG[2]; const __bf16* gU[2];
    __bf16* lG[2]; __bf16* lU[2];
    #pragma unroll
    for (int s = 0; s < 2; s++) {
        const int f = wave * 16 + s * 8 + srow;
        gG[s] = wgT + ((size_t)e * F_DIM + n0 + f) * H_DIM + selem;
        gU[s] = wuT + ((size_t)e * F_DIM + n0 + f) * H_DIM + selem;
        lG[s] = &Bgs[(wave * 16 + s * 8) * BK];
        lU[s] = &Bus[(wave * 16 + s * 8) * BK];
    }

    f32x4 accg[4][2] = {};
    f32x4 accu[4][2] = {};

    for (int k0 = 0; k0 < H_DIM; k0 += BK) {
        __syncthreads();
        #pragma unroll
        for (int s = 0; s < 4; s++) async_cp16(gA[s] + k0, lA[s]);
        #pragma unroll
        for (int s = 0; s < 2; s++) {
            async_cp16(gG[s] + k0, lG[s]);
            async_cp16(gU[s] + k0, lU[s]);
        }
        __syncthreads();   // compiler emits s_waitcnt vmcnt(0) before s_barrier

        #pragma unroll
        for (int ks = 0; ks < 2; ks++) {
            bf16x8 af[4], bg[2], bu[2];
            #pragma unroll
            for (int i = 0; i < 4; i++)
                af[i] = *(const bf16x8*)(&As[(wm0 + i * 16 + ln) * BK + ks * 32 + q * 8]);
            #pragma unroll
            for (int j = 0; j < 2; j++) {
                bg[j] = *(const bf16x8*)(&Bgs[(wn0 + j * 16 + ln) * BK + ks * 32 + q * 8]);
                bu[j] = *(const bf16x8*)(&Bus[(wn0 + j * 16 + ln) * BK + ks * 32 + q * 8]);
            }
            #pragma unroll
            for (int i = 0; i < 4; i++)
                #pragma unroll
                for (int j = 0; j < 2; j++) {
                    accg[i][j] = __builtin_amdgcn_mfma_f32_16x16x32_bf16(af[i], bg[j], accg[i][j], 0, 0, 0);
                    accu[i][j] = __builtin_amdgcn_mfma_f32_16x16x32_bf16(af[i], bu[j], accu[i][j], 0, 0, 0);
                }
        }
    }

    // epilogue: h = silu(g) * u -> bf16 (rows >= count hold finite garbage, discarded downstream)
    #pragma unroll
    for (int i = 0; i < 4; i++) {
        const int mb = m0 + wm0 + i * 16 + q * 4;
        #pragma unroll
        for (int j = 0; j < 2; j++) {
            const int fc = n0 + wn0 + j * 16 + ln;
            #pragma unroll
            for (int r = 0; r < 4; r++) {
                float g = accg[i][j][r];
                float u = accu[i][j][r];
                float s = g / (1.f + __expf(-g));
                hbuf[((size_t)e * C_CAP + (mb + r)) * F_DIM + fc] = (__bf16)(s * u);
            }
        }
    }
}

// down GEMM + weighted scatter-combine into y (fp32 atomics)
__global__ __launch_bounds__(256) void gemm_down(
    const __bf16* __restrict__ hbuf, const __bf16* __restrict__ wdT,
    const int* __restrict__ gtok, const float* __restrict__ gwt,
    const int* __restrict__ counts, float* __restrict__ y)
{
    const int e = blockIdx.z;
    const int count = counts[e];
    const int m0 = blockIdx.y * BM;
    if (m0 >= count) return;
    const int n0 = blockIdx.x * BN2;

    __shared__ __bf16 As[BM  * BK];    // 16 KB
    __shared__ __bf16 Bs[BN2 * BK];    // 16 KB

    const int tid  = threadIdx.x;
    const int lane = tid & 63;
    const int wave = tid >> 6;
    const int wm0 = (wave & 1) * 64;
    const int wn0 = (wave >> 1) * 64;
    const int q  = lane >> 4;
    const int ln = lane & 15;

    const int srow = lane >> 3;
    const int selem = (lane & 7) * 8;

    const __bf16* gA[4]; const __bf16* gB[4];
    __bf16* lA[4]; __bf16* lB[4];
    #pragma unroll
    for (int s = 0; s < 4; s++) {
        const int r = wave * 32 + s * 8 + srow;
        gA[s] = hbuf + ((size_t)e * C_CAP + m0 + r) * F_DIM + selem;
        lA[s] = &As[(wave * 32 + s * 8) * BK];
        gB[s] = wdT + ((size_t)e * H_DIM + n0 + r) * F_DIM + selem;
        lB[s] = &Bs[(wave * 32 + s * 8) * BK];
    }

    f32x4 acc[4][4] = {};

    for (int k0 = 0; k0 < F_DIM; k0 += BK) {
        __syncthreads();
        #pragma unroll
        for (int s = 0; s < 4; s++) {
            async_cp16(gA[s] + k0, lA[s]);
            async_cp16(gB[s] + k0, lB[s]);
        }
        __syncthreads();

        #pragma unroll
        for (int ks = 0; ks < 2; ks++) {
            bf16x8 af[4], bb[4];
            #pragma unroll
            for (int i = 0; i < 4; i++)
                af[i] = *(const bf16x8*)(&As[(wm0 + i * 16 + ln) * BK + ks * 32 + q * 8]);
            #pragma unroll
            for (int j = 0; j < 4; j++)
                bb[j] = *(const bf16x8*)(&Bs[(wn0 + j * 16 + ln) * BK + ks * 32 + q * 8]);
            #pragma unroll
            for (int i = 0; i < 4; i++)
                #pragma unroll
                for (int j = 0; j < 4; j++)
                    acc[i][j] = __builtin_amdgcn_mfma_f32_16x16x32_bf16(af[i], bb[j], acc[i][j], 0, 0, 0);
        }
    }

    #pragma unroll
    for (int i = 0; i < 4; i++) {
        const int mb = wm0 + i * 16 + q * 4;
        int tokr[4]; float wtr[4];
        #pragma unroll
        for (int r = 0; r < 4; r++) {
            const int row = m0 + mb + r;
            const bool v = row < count;
            tokr[r] = v ? gtok[e * C_CAP + row] : -1;
            wtr[r]  = v ? gwt[e * C_CAP + row] : 0.f;
        }
        #pragma unroll
        for (int j = 0; j < 4; j++) {
            const int hc = n0 + wn0 + j * 16 + ln;
            #pragma unroll
            for (int r = 0; r < 4; r++) {
                if (tokr[r] >= 0)
                    atomicAdd(&y[(size_t)tokr[r] * H_DIM + hc], acc[i][j][r] * wtr[r]);
            }
        }
    }
}

extern "C" void kernel_launch(void* const* d_in, const int* in_sizes, int n_in,
                              void* d_out, int out_size, void* d_ws, size_t ws_size,
                              hipStream_t stream)
{
    const float* x    = (const float*)d_in[0];
    const float* wr   = (const float*)d_in[1];
    const float* bias = (const float*)d_in[2];
    const float* wg   = (const float*)d_in[3];
    const float* wu   = (const float*)d_in[4];
    const float* wd   = (const float*)d_in[5];

    float* y      = (float*)d_out;
    float* logits = y + (size_t)T_TOK * H_DIM;
    float* idxo   = logits + (size_t)T_TOK * E_EXP;   // float values (harness reads f32)

    char* ws = (char*)d_ws;
    float*  wt_buf = (float*)(ws + OFF_WT);
    float*  gwt    = (float*)(ws + OFF_GWT);
    int*    gtok   = (int*)(ws + OFF_GTOK);
    unsigned long long* masks = (unsigned long long*)(ws + OFF_MASKS);
    int*    counts = (int*)(ws + OFF_COUNTS);
    __bf16* xb   = (__bf16*)(ws + OFF_XB);
    __bf16* wgT  = (__bf16*)(ws + OFF_WGT);
    __bf16* wuT  = (__bf16*)(ws + OFF_WUT);
    __bf16* wdT  = wuT;                       // reuses w_up region after gemm_gateup
    __bf16* hbuf = (__bf16*)(ws + OFF_HBUF);

    hipMemsetAsync(d_out, 0, (size_t)T_TOK * H_DIM * sizeof(float), stream);

    router_kernel<<<T_TOK, 64, 0, stream>>>(x, wr, bias, logits, idxo, wt_buf, masks, xb);
    scan_kernel<<<E_EXP, 64, 0, stream>>>(masks, idxo, wt_buf, gtok, gwt, counts);

    // w_gate & w_up: [E][H][F] -> [E][F][H], fused into one launch
    transpose_cast2<<<dim3(F_DIM / 32, H_DIM / 32, 2 * E_EXP), 256, 0, stream>>>(
        wg, wgT, wu, wuT, H_DIM, F_DIM);

    gemm_gateup<<<dim3(F_DIM / BN1, C_CAP / BM, E_EXP), 256, 0, stream>>>(
        xb, wgT, wuT, gtok, counts, hbuf);

    // w_down: [E][F][H] -> [E][H][F], into wuT region (dead after gemm_gateup)
    transpose_cast2<<<dim3(H_DIM / 32, F_DIM / 32, E_EXP), 256, 0, stream>>>(
        wd, wdT, wd, wdT, F_DIM, H_DIM);

    gemm_down<<<dim3(H_DIM / BN2, C_CAP / BM, E_EXP), 256, 0, stream>>>(
        hbuf, wdT, gtok, gwt, counts, y);
}